// Round 7
// baseline (1928.615 us; speedup 1.0000x reference)
//
#include <hip/hip_runtime.h>
#include <math.h>

// LSTM persistent kernel, R22: R15 (best verified: 1688us) with staggered
// gate-chain completion to hide the tail inside the matrix phase.
//
// Model correction (R15/R19/R21 ledger): tail-issue cuts (515->402->420
// cy/SIMD) never moved the wall; chain-lengthening always hurt. R15's
// ~478cy non-matrix wall is serial LATENCY (act chain + c-chain + LDS h
// turnaround), filled by -- not caused by -- tail issue. Root cause of
// zero overlap: c-major MFMA order completes all 4 gate chains in the
// last issue slots + in-order wave => strict [matrix][tail] phase lock.
//
// R22: split MFMAs into {f,g,o} (12, 3-way interleaved) and {i} (4);
// place each block's activations between blocks, pinned by
// sched_barrier(0). Waves 0-3 and 4-7 use MIRRORED block orders so the
// per-SIMD wave pair (w, w+4) hits VALU windows at different times: one
// wave's acts issue while the other feeds the matrix pipe (m114 overlap,
// manufactured inside a lockstep block). Exposed serial remainder: one
// act (~52cy) + c-chain (~80) + turnaround (~175).
//
// All per-gate arithmetic identical ops in identical order vs R15 =>
// absmax must stay exactly 2.4414e-4.
//
// Prediction: wall 990 -> ~820-880cy, dur -> ~1400-1500us; MfmaUtil AND
// VALUBusy both rise (~14.5-15.5 reported) -- the overlap fingerprint.
// Falsifier: dur >= 1650 => lockstep defeated the stagger; only
// precision-format changes remain.
constexpr int Hdim = 128;
constexpr int TMAX = 4096;

typedef _Float16 v8h __attribute__((ext_vector_type(8)));
typedef float v4f __attribute__((ext_vector_type(4)));

#if __has_builtin(__builtin_amdgcn_exp2f)
__device__ __forceinline__ float exp2_fast(float x) {
  return __builtin_amdgcn_exp2f(x);
}
#else
__device__ __forceinline__ float exp2_fast(float x) {
  return __expf(x * 0.6931471805599453f);
}
#endif

__device__ __forceinline__ float rcp_fast(float x) {
  return __builtin_amdgcn_rcpf(x);
}

__device__ __forceinline__ void sb0() {
#if __has_builtin(__builtin_amdgcn_sched_barrier)
  __builtin_amdgcn_sched_barrier(0);
#endif
}

__device__ __forceinline__ float sel4(v4f d, int r) {
  const float s01 = (r & 1) ? d.y : d.x;
  const float s23 = (r & 1) ? d.w : d.z;
  return (r & 2) ? s23 : s01;
}

#define MF(A, B, C) __builtin_amdgcn_mfma_f32_16x16x32_f16((A), (B), (C), 0, 0, 0)

// One LSTM step for this lane's element. ORDER 0: chains {f,g,o} first,
// {i} last (act i exposed). ORDER 1: mirrored. Returns h; updates cst.
template <int ORDER>
__device__ __forceinline__ float step_body(const v8h a[4][4], const v8h bq[4],
                                           const v4f acc_init[4],
                                           const float* wih, float xt, int r,
                                           float& cst) {
  constexpr float L2E = 1.44269504088896f;
  float yi, yf, ug, yo;

  if (ORDER == 0) {
    // Block A: gates f,g,o -- 12 MFMAs, 3-way chunk-interleaved.
    v4f d1 = MF(a[1][0], bq[0], acc_init[1]);
    v4f d2 = MF(a[2][0], bq[0], acc_init[2]);
    v4f d3 = MF(a[3][0], bq[0], acc_init[3]);
#pragma unroll
    for (int c = 1; c < 4; ++c) {
      d1 = MF(a[1][c], bq[c], d1);
      d2 = MF(a[2][c], bq[c], d2);
      d3 = MF(a[3][c], bq[c], d3);
    }
    // Acts for f,g,o (3-way ILP) -- other wave is in its MFMA block.
    yf = rcp_fast(1.0f + exp2_fast(fmaf(xt, wih[1], sel4(d1, r))));
    ug = rcp_fast(1.0f + exp2_fast(fmaf(xt, wih[2], sel4(d2, r))));
    yo = rcp_fast(1.0f + exp2_fast(fmaf(xt, wih[3], sel4(d3, r))));
    sb0();
    // Block B: gate i -- 4 MFMAs (dependent chain; other wave's MFMAs
    // fill the pipe gaps).
    v4f d0 = MF(a[0][0], bq[0], acc_init[0]);
#pragma unroll
    for (int c = 1; c < 4; ++c) d0 = MF(a[0][c], bq[c], d0);
    yi = rcp_fast(1.0f + exp2_fast(fmaf(xt, wih[0], sel4(d0, r))));
  } else {
    // Mirrored: gate i first, then f,g,o.
    v4f d0 = MF(a[0][0], bq[0], acc_init[0]);
#pragma unroll
    for (int c = 1; c < 4; ++c) d0 = MF(a[0][c], bq[c], d0);
    yi = rcp_fast(1.0f + exp2_fast(fmaf(xt, wih[0], sel4(d0, r))));
    sb0();
    v4f d1 = MF(a[1][0], bq[0], acc_init[1]);
    v4f d2 = MF(a[2][0], bq[0], acc_init[2]);
    v4f d3 = MF(a[3][0], bq[0], acc_init[3]);
#pragma unroll
    for (int c = 1; c < 4; ++c) {
      d1 = MF(a[1][c], bq[c], d1);
      d2 = MF(a[2][c], bq[c], d2);
      d3 = MF(a[3][c], bq[c], d3);
    }
    yf = rcp_fast(1.0f + exp2_fast(fmaf(xt, wih[1], sel4(d1, r))));
    ug = rcp_fast(1.0f + exp2_fast(fmaf(xt, wih[2], sel4(d2, r))));
    yo = rcp_fast(1.0f + exp2_fast(fmaf(xt, wih[3], sel4(d3, r))));
  }

  // c-chain (identical ops/order vs R15).
  const float yg = fmaf(-2.0f, ug, 1.0f);  // tanh(raw_g)
  cst = fmaf(yf, cst, yi * yg);            // c = f*c + i*g
  const float th =
      fmaf(-2.0f, rcp_fast(1.0f + exp2_fast(cst * (2.0f * L2E))), 1.0f);
  return yo * th;  // h = o * tanh(c)
}

__global__ __launch_bounds__(512) void lstm_r22(
    const float* __restrict__ data, const float* __restrict__ h0,
    const float* __restrict__ c0, const float* __restrict__ W_ih,
    const float* __restrict__ W_hh, const float* __restrict__ b_ih,
    const float* __restrict__ b_hh, const float* __restrict__ W_out,
    const float* __restrict__ b_out, float* __restrict__ out, int T) {
  __shared__ __align__(16) float xs[TMAX];
  __shared__ __align__(16) _Float16 hbuf[2][Hdim];

  const int b = blockIdx.x;
  const int tid = threadIdx.x;
  const int lane = tid & 63;
  const int wv = tid >> 6;  // wave 0..7 owns elements 16wv..16wv+15
  const int p = lane >> 4;  // 0..3
  const int m = lane & 15;  // column id (all D cols identical)
  const int r = m & 3;      // which d-component this lane's tail handles
  const int el = 16 * wv + 4 * p + r;  // my tail element

  // Stage input row (coalesced float4).
  {
    const float4* src = (const float4*)(data + (size_t)b * T);
    float4* dst = (float4*)xs;
    for (int i = tid; i < T / 4; i += 512) dst[i] = src[i];
  }

  constexpr float L2E = 1.44269504088896f;

  // A-frags: gate g -> rows [128g+16wv, 128g+16wv+16), chunk c -> k in
  // [32c,32c+32). Lane holds A[m][32c+8p+j], j=0..7, pre-scaled by Mk(g).
  v8h a[4][4];
#pragma unroll
  for (int g = 0; g < 4; ++g) {
    const int row = 128 * g + 16 * wv + m;
    const float Mr = (g == 2) ? 2.0f * L2E : -L2E;
    const float* wr = W_hh + (size_t)row * Hdim + 8 * p;
#pragma unroll
    for (int c = 0; c < 4; ++c) {
      float4 v0 = ((const float4*)(wr + 32 * c))[0];
      float4 v1 = ((const float4*)(wr + 32 * c))[1];
      a[g][c] = v8h{(_Float16)(Mr * v0.x), (_Float16)(Mr * v0.y),
                    (_Float16)(Mr * v0.z), (_Float16)(Mr * v0.w),
                    (_Float16)(Mr * v1.x), (_Float16)(Mr * v1.y),
                    (_Float16)(Mr * v1.z), (_Float16)(Mr * v1.w)};
    }
  }

  // Bias seeds: acc_init[g].reg = Mk(g)*(b_ih+b_hh) of row 128g+16wv+4p+reg.
  v4f acc_init[4];
#pragma unroll
  for (int g = 0; g < 4; ++g) {
    const float Mr = (g == 2) ? 2.0f * L2E : -L2E;
    const int row = 128 * g + 16 * wv + 4 * p;
    acc_init[g] = v4f{Mr * (b_ih[row + 0] + b_hh[row + 0]),
                      Mr * (b_ih[row + 1] + b_hh[row + 1]),
                      Mr * (b_ih[row + 2] + b_hh[row + 2]),
                      Mr * (b_ih[row + 3] + b_hh[row + 3])};
  }

  // Tail constants: Mk-scaled W_ih for my element, per gate.
  float wih[4];
#pragma unroll
  for (int g = 0; g < 4; ++g) {
    const float Mr = (g == 2) ? 2.0f * L2E : -L2E;
    wih[g] = Mr * W_ih[128 * g + el];
  }

  float cst = c0[(size_t)b * Hdim + el];
  if (tid < 128) hbuf[0][tid] = (_Float16)h0[(size_t)b * Hdim + tid];
  __syncthreads();

  for (int t0 = 0; t0 < T; t0 += 4) {
    const float4 xv = *(const float4*)&xs[t0];  // 4 steps of x, one read
    const float xts[4] = {xv.x, xv.y, xv.z, xv.w};
#pragma unroll
    for (int u = 0; u < 4; ++u) {
      const int t = t0 + u;
      const _Float16* hb = hbuf[t & 1];
      _Float16* hn = hbuf[(t + 1) & 1];
      // B-frags: h chunk c, lane reads h[32c+8p+j] (16-lane broadcast).
      v8h bq[4];
#pragma unroll
      for (int c = 0; c < 4; ++c) bq[c] = *(const v8h*)(hb + 32 * c + 8 * p);
      const float xt = xts[u];

      float h;
      if (wv < 4) {
        h = step_body<0>(a, bq, acc_init, wih, xt, r, cst);
      } else {
        h = step_body<1>(a, bq, acc_init, wih, xt, r, cst);
      }

      if (m < 4) hn[el] = (_Float16)h;
      __syncthreads();
    }
  }

  // Final linear: out[b] = h_T . W_out + b_out (wave 0).
  if (tid < 64) {
    const _Float16* hf = hbuf[T & 1];
    float sum =
        (float)hf[tid] * W_out[tid] + (float)hf[tid + 64] * W_out[tid + 64];
#pragma unroll
    for (int off = 32; off > 0; off >>= 1) sum += __shfl_down(sum, off, 64);
    if (tid == 0) out[b] = sum + b_out[0];
  }
}

extern "C" void kernel_launch(void* const* d_in, const int* in_sizes, int n_in,
                              void* d_out, int out_size, void* d_ws,
                              size_t ws_size, hipStream_t stream) {
  const float* data = (const float*)d_in[0];
  const float* h0 = (const float*)d_in[1];
  const float* c0 = (const float*)d_in[2];
  const float* W_ih = (const float*)d_in[3];
  const float* W_hh = (const float*)d_in[4];
  const float* b_ih = (const float*)d_in[5];
  const float* b_hh = (const float*)d_in[6];
  const float* W_out = (const float*)d_in[7];
  const float* b_out = (const float*)d_in[8];
  float* out = (float*)d_out;

  const int B = in_sizes[1] / Hdim;  // 64
  const int T = in_sizes[0] / B;     // 4096

  lstm_r22<<<B, 512, 0, stream>>>(data, h0, c0, W_ih, W_hh, b_ih, b_hh, W_out,
                                  b_out, out, T);
}